// Round 1
// baseline (364.702 us; speedup 1.0000x reference)
//
#include <hip/hip_runtime.h>
#include <math.h>

#define CNUM 19
#define NB 4
#define HW 589824            // 768*768
#define NPIX 2359296         // NB*HW

// ---------------------------------------------------------------- workspace
struct Ws {
  unsigned int hist_seg[NB][CNUM];   // per-image class histogram of segmask
  unsigned int hist_att[NB][CNUM];   // per-image class histogram where edge>0.8
  unsigned int pos_num;              // edgemask == 1 count (global)
  unsigned int neg_num;              // edgemask == 0 count (global)
  float w_seg[NB][CNUM];
  float w_att[NB][CNUM];
  double num_seg[NB];
  double den_seg[NB];
  double num_att[NB];
  double den_att[NB];
  double bce_sum;
};

// ---------------------------------------------------------------- init: zero ws
__global__ void k_init(Ws* ws) {
  unsigned int* p = (unsigned int*)ws;
  const int nwords = (int)(sizeof(Ws) / 4);
  for (int i = threadIdx.x; i < nwords; i += blockDim.x) p[i] = 0u;
}

// ---------------------------------------------------------------- histograms
// 1024 blocks x 256 threads, 9 iterations: exactly NPIX, no tail.
__global__ __launch_bounds__(256) void k_hist(const int* __restrict__ segmask,
                                              const float* __restrict__ edgein,
                                              const int* __restrict__ edgemask,
                                              Ws* ws) {
  __shared__ unsigned int sh[2 * NB * CNUM + 2];
  for (int i = threadIdx.x; i < 2 * NB * CNUM + 2; i += 256) sh[i] = 0u;
  __syncthreads();
  unsigned int* sh_seg = sh;
  unsigned int* sh_att = sh + NB * CNUM;
  unsigned int* sh_pn  = sh + 2 * NB * CNUM;
  const int lane = threadIdx.x & 63;
  const int base0 = blockIdx.x * 256 + threadIdx.x;
  #pragma unroll
  for (int it = 0; it < 9; ++it) {
    int idx = base0 + it * (1024 * 256);
    int n = idx / HW;
    int s = segmask[idx];
    float e = edgein[idx];
    int em = edgemask[idx];
    bool inb = (s >= 0) && (s < CNUM);
    if (inb) atomicAdd(&sh_seg[n * CNUM + s], 1u);
    if (inb && (e > 0.8f)) atomicAdd(&sh_att[n * CNUM + s], 1u);
    unsigned long long bp = __ballot(em == 1);
    unsigned long long bn = __ballot(em == 0);
    if (lane == 0) {
      atomicAdd(&sh_pn[0], (unsigned int)__popcll(bp));
      atomicAdd(&sh_pn[1], (unsigned int)__popcll(bn));
    }
  }
  __syncthreads();
  for (int i = threadIdx.x; i < NB * CNUM; i += 256) {
    if (sh_seg[i]) atomicAdd(&((unsigned int*)ws->hist_seg)[i], sh_seg[i]);
    if (sh_att[i]) atomicAdd(&((unsigned int*)ws->hist_att)[i], sh_att[i]);
  }
  if (threadIdx.x == 0)  atomicAdd(&ws->pos_num, sh_pn[0]);
  if (threadIdx.x == 64) atomicAdd(&ws->neg_num, sh_pn[1]);
}

// ---------------------------------------------------------------- weights
__global__ void k_weights(Ws* ws) {
  int t = threadIdx.x;
  if (t < 2 * NB * CNUM) {
    int which = t / (NB * CNUM);
    int r = t % (NB * CNUM);
    int n = r / CNUM, c = r % CNUM;
    const unsigned int* h = which ? ws->hist_att[n] : ws->hist_seg[n];
    float total = 0.f;
    #pragma unroll
    for (int i = 0; i < CNUM; ++i) total += (float)h[i];
    float bins = (float)h[c];
    float w = (bins != 0.f ? (1.0f - bins / total) : 0.f) + 1.0f;
    if (which) ws->w_att[n][c] = w;
    else       ws->w_seg[n][c] = w;
  }
}

// ---------------------------------------------------------------- main pass
// grid (HW/1024, NB) x 256 threads; each thread handles 4 consecutive pixels.
__global__ __launch_bounds__(256) void k_main(const float* __restrict__ segin,
                                              const float* __restrict__ edgein,
                                              const int* __restrict__ segmask,
                                              const int* __restrict__ edgemask,
                                              Ws* __restrict__ ws) {
  const int n = blockIdx.y;
  const int hw4 = (blockIdx.x * 256 + threadIdx.x) * 4;
  const int idx4 = n * HW + hw4;
  const float* base = segin + (size_t)n * CNUM * HW + hw4;

  float x[CNUM][4];
  #pragma unroll
  for (int c = 0; c < CNUM; ++c) {
    float4 v = *reinterpret_cast<const float4*>(base + (size_t)c * HW);
    x[c][0] = v.x; x[c][1] = v.y; x[c][2] = v.z; x[c][3] = v.w;
  }
  int4   tm = *reinterpret_cast<const int4*>(segmask + idx4);
  float4 ev = *reinterpret_cast<const float4*>(edgein + idx4);
  int4   em = *reinterpret_cast<const int4*>(edgemask + idx4);
  int   tarr[4]  = {tm.x, tm.y, tm.z, tm.w};
  float earr[4]  = {ev.x, ev.y, ev.z, ev.w};
  int   emarr[4] = {em.x, em.y, em.z, em.w};

  const unsigned int pn = ws->pos_num, nn = ws->neg_num;
  const float inv_sum = 1.0f / (float)(pn + nn);
  const float wpos = (float)nn * inv_sum;
  const float wneg = (float)pn * inv_sum;

  float acc_num_s = 0.f, acc_den_s = 0.f, acc_num_a = 0.f, acc_den_a = 0.f, acc_bce = 0.f;
  #pragma unroll
  for (int p = 0; p < 4; ++p) {
    int t = tarr[p];
    int tc = min(max(t, 0), CNUM - 1);
    float m = x[0][p];
    #pragma unroll
    for (int c = 1; c < CNUM; ++c) m = fmaxf(m, x[c][p]);
    float s = 0.f;
    #pragma unroll
    for (int c = 0; c < CNUM; ++c) s += __expf(x[c][p] - m);
    float lse = m + __logf(s);
    float xt = x[0][p];
    #pragma unroll
    for (int c = 1; c < CNUM; ++c) xt = (tc == c) ? x[c][p] : xt;
    float lp = xt - lse;

    bool validt = (t != 255);
    float pw_s = validt ? ws->w_seg[n][tc] : 0.f;
    acc_num_s -= pw_s * lp;
    acc_den_s += pw_s;

    float e = earr[p];
    bool valida = validt && (e > 0.8f);
    float pw_a = valida ? ws->w_att[n][tc] : 0.f;
    acc_num_a -= pw_a * lp;
    acc_den_a += pw_a;

    int emv = emarr[p];
    float tf = (float)emv;
    float wb = (emv == 1) ? wpos : ((emv == 0) ? wneg : 0.f);
    float bce = fmaxf(e, 0.f) - e * tf + log1pf(__expf(-fabsf(e)));
    acc_bce += wb * bce;
  }

  // wave (64-lane) shuffle reduction, then cross-wave via LDS
  #pragma unroll
  for (int off = 32; off > 0; off >>= 1) {
    acc_num_s += __shfl_down(acc_num_s, off);
    acc_den_s += __shfl_down(acc_den_s, off);
    acc_num_a += __shfl_down(acc_num_a, off);
    acc_den_a += __shfl_down(acc_den_a, off);
    acc_bce   += __shfl_down(acc_bce, off);
  }
  __shared__ float red[4][5];
  const int wave = threadIdx.x >> 6;
  const int lane = threadIdx.x & 63;
  if (lane == 0) {
    red[wave][0] = acc_num_s; red[wave][1] = acc_den_s;
    red[wave][2] = acc_num_a; red[wave][3] = acc_den_a;
    red[wave][4] = acc_bce;
  }
  __syncthreads();
  if (threadIdx.x == 0) {
    float r0 = 0.f, r1 = 0.f, r2 = 0.f, r3 = 0.f, r4 = 0.f;
    #pragma unroll
    for (int wv = 0; wv < 4; ++wv) {
      r0 += red[wv][0]; r1 += red[wv][1]; r2 += red[wv][2];
      r3 += red[wv][3]; r4 += red[wv][4];
    }
    atomicAdd(&ws->num_seg[n], (double)r0);
    atomicAdd(&ws->den_seg[n], (double)r1);
    atomicAdd(&ws->num_att[n], (double)r2);
    atomicAdd(&ws->den_att[n], (double)r3);
    atomicAdd(&ws->bce_sum,    (double)r4);
  }
}

// ---------------------------------------------------------------- finalize
__global__ void k_final(const Ws* __restrict__ ws, float* __restrict__ out) {
  if (threadIdx.x == 0 && blockIdx.x == 0) {
    double segl = 0.0, attl = 0.0;
    for (int i = 0; i < NB; ++i) {
      segl += ws->num_seg[i] / ws->den_seg[i];
      attl += ws->num_att[i] / ws->den_att[i];
    }
    double edgel = ws->bce_sum / (double)NPIX;
    out[0] = (float)(1.0 * segl + 0.3 * edgel + 0.1 * attl);
  }
}

// ---------------------------------------------------------------- launch
extern "C" void kernel_launch(void* const* d_in, const int* in_sizes, int n_in,
                              void* d_out, int out_size, void* d_ws, size_t ws_size,
                              hipStream_t stream) {
  const float* segin   = (const float*)d_in[0];
  const float* edgein  = (const float*)d_in[1];
  const int*   segmask = (const int*)d_in[2];
  const int*   edgemask= (const int*)d_in[3];
  Ws* ws = (Ws*)d_ws;
  float* out = (float*)d_out;

  hipLaunchKernelGGL(k_init,    dim3(1),            dim3(256), 0, stream, ws);
  hipLaunchKernelGGL(k_hist,    dim3(1024),         dim3(256), 0, stream, segmask, edgein, edgemask, ws);
  hipLaunchKernelGGL(k_weights, dim3(1),            dim3(256), 0, stream, ws);
  hipLaunchKernelGGL(k_main,    dim3(HW / 1024, NB), dim3(256), 0, stream, segin, edgein, segmask, edgemask, ws);
  hipLaunchKernelGGL(k_final,   dim3(1),            dim3(1),   0, stream, ws, out);
}

// Round 2
// 355.814 us; speedup vs baseline: 1.0250x; 1.0250x over previous
//
#include <hip/hip_runtime.h>
#include <math.h>

#define CNUM 19
#define NB 4
#define HW 589824            // 768*768
#define NPIX 2359296         // NB*HW

// ---------------------------------------------------------------- workspace
struct Ws {
  unsigned int hist_seg[NB][CNUM];   // per-image class histogram of segmask
  unsigned int hist_att[NB][CNUM];   // per-image class histogram where edge>0.8
  unsigned int pos_num;              // edgemask == 1 count (global)
  unsigned int neg_num;              // edgemask == 0 count (global)
  float w_seg[NB][CNUM];
  float w_att[NB][CNUM];
  double num_seg[NB];
  double den_seg[NB];
  double num_att[NB];
  double den_att[NB];
  double bce_sum;
};

// ---------------------------------------------------------------- init: zero ws
__global__ void k_init(Ws* ws) {
  unsigned int* p = (unsigned int*)ws;
  const int nwords = (int)(sizeof(Ws) / 4);
  for (int i = threadIdx.x; i < nwords; i += blockDim.x) p[i] = 0u;
}

// ---------------------------------------------------------------- histograms
// Ballot-based: no atomics in the hot loop. grid (HW/4096, NB) x 256.
// Each thread: 4 iterations x int4 = 16 pixels. Counts are wave-uniform.
__global__ __launch_bounds__(256) void k_hist(const int* __restrict__ segmask,
                                              const float* __restrict__ edgein,
                                              const int* __restrict__ edgemask,
                                              Ws* __restrict__ ws) {
  const int n  = blockIdx.y;
  const int bx = blockIdx.x;
  const int tid = threadIdx.x;
  const int base = n * HW + bx * 4096 + tid * 4;

  unsigned int cs[CNUM], ca[CNUM];
  #pragma unroll
  for (int c = 0; c < CNUM; ++c) { cs[c] = 0u; ca[c] = 0u; }
  unsigned int cp = 0u, cn = 0u;

  #pragma unroll
  for (int it = 0; it < 4; ++it) {
    const int idx = base + it * 1024;
    int4   sv = *reinterpret_cast<const int4*>(segmask + idx);
    float4 e  = *reinterpret_cast<const float4*>(edgein + idx);
    int4   mv = *reinterpret_cast<const int4*>(edgemask + idx);
    int   sa[4] = {sv.x, sv.y, sv.z, sv.w};
    float ea[4] = {e.x, e.y, e.z, e.w};
    int   ma[4] = {mv.x, mv.y, mv.z, mv.w};
    #pragma unroll
    for (int p = 0; p < 4; ++p) {
      const int s = sa[p];
      const bool inb = ((unsigned)s) < (unsigned)CNUM;
      const bool att = inb && (ea[p] > 0.8f);
      #pragma unroll
      for (int c = 0; c < CNUM; ++c) {
        cs[c] += (unsigned)__popcll(__ballot(inb && (s == c)));
        ca[c] += (unsigned)__popcll(__ballot(att && (s == c)));
      }
      cp += (unsigned)__popcll(__ballot(ma[p] == 1));
      cn += (unsigned)__popcll(__ballot(ma[p] == 0));
    }
  }

  // cross-wave reduce in LDS, then <=40 global atomics per block
  __shared__ unsigned int red[4][2 * CNUM + 2];
  const int wave = tid >> 6;
  const int lane = tid & 63;
  if (lane == 0) {
    #pragma unroll
    for (int c = 0; c < CNUM; ++c) { red[wave][c] = cs[c]; red[wave][CNUM + c] = ca[c]; }
    red[wave][2 * CNUM] = cp;
    red[wave][2 * CNUM + 1] = cn;
  }
  __syncthreads();
  if (tid < 2 * CNUM + 2) {
    unsigned int v = red[0][tid] + red[1][tid] + red[2][tid] + red[3][tid];
    if (tid < CNUM)               atomicAdd(&ws->hist_seg[n][tid], v);
    else if (tid < 2 * CNUM)      atomicAdd(&ws->hist_att[n][tid - CNUM], v);
    else if (tid == 2 * CNUM)     atomicAdd(&ws->pos_num, v);
    else                          atomicAdd(&ws->neg_num, v);
  }
}

// ---------------------------------------------------------------- weights
__global__ void k_weights(Ws* ws) {
  int t = threadIdx.x;
  if (t < 2 * NB * CNUM) {
    int which = t / (NB * CNUM);
    int r = t % (NB * CNUM);
    int n = r / CNUM, c = r % CNUM;
    const unsigned int* h = which ? ws->hist_att[n] : ws->hist_seg[n];
    float total = 0.f;
    #pragma unroll
    for (int i = 0; i < CNUM; ++i) total += (float)h[i];
    float bins = (float)h[c];
    float w = (bins != 0.f ? (1.0f - bins / total) : 0.f) + 1.0f;
    if (which) ws->w_att[n][c] = w;
    else       ws->w_seg[n][c] = w;
  }
}

// ---------------------------------------------------------------- main pass
// grid (HW/1024, NB) x 256 threads; each thread handles 4 consecutive pixels.
// Online sum-exp (no max subtraction; inputs are O(1) so fp32 exp is safe):
// tiny register working set -> deep load pipelining.
__global__ __launch_bounds__(256) void k_main(const float* __restrict__ segin,
                                              const float* __restrict__ edgein,
                                              const int* __restrict__ segmask,
                                              const int* __restrict__ edgemask,
                                              const Ws* __restrict__ ws,
                                              Ws* __restrict__ wsw) {
  const int n = blockIdx.y;
  const int tid = threadIdx.x;
  const int hw4 = (blockIdx.x * 256 + tid) * 4;
  const int idx4 = n * HW + hw4;
  const float* base = segin + (size_t)n * CNUM * HW + hw4;

  // stage per-image class weights in LDS (dynamic index per pixel)
  __shared__ float lws[CNUM], lwa[CNUM];
  if (tid < CNUM) lws[tid] = ws->w_seg[n][tid];
  else if (tid >= 64 && tid < 64 + CNUM) lwa[tid - 64] = ws->w_att[n][tid - 64];
  __syncthreads();

  int4   tm = *reinterpret_cast<const int4*>(segmask + idx4);
  float4 ev = *reinterpret_cast<const float4*>(edgein + idx4);
  int4   em = *reinterpret_cast<const int4*>(edgemask + idx4);
  int   tarr[4]  = {tm.x, tm.y, tm.z, tm.w};
  float earr[4]  = {ev.x, ev.y, ev.z, ev.w};
  int   emarr[4] = {em.x, em.y, em.z, em.w};

  int tc[4];
  #pragma unroll
  for (int p = 0; p < 4; ++p) tc[p] = min(max(tarr[p], 0), CNUM - 1);

  float s[4]  = {0.f, 0.f, 0.f, 0.f};
  float xt[4] = {0.f, 0.f, 0.f, 0.f};
  #pragma unroll
  for (int c = 0; c < CNUM; ++c) {
    float4 v = *reinterpret_cast<const float4*>(base + (size_t)c * HW);
    float va[4] = {v.x, v.y, v.z, v.w};
    #pragma unroll
    for (int p = 0; p < 4; ++p) {
      s[p] += __expf(va[p]);
      xt[p] = (tc[p] == c) ? va[p] : xt[p];
    }
  }

  const unsigned int pn = ws->pos_num, nn = ws->neg_num;
  const float inv_sum = 1.0f / (float)(pn + nn);
  const float wpos = (float)nn * inv_sum;
  const float wneg = (float)pn * inv_sum;

  float acc_num_s = 0.f, acc_den_s = 0.f, acc_num_a = 0.f, acc_den_a = 0.f, acc_bce = 0.f;
  #pragma unroll
  for (int p = 0; p < 4; ++p) {
    float lp = xt[p] - __logf(s[p]);
    bool validt = (tarr[p] != 255);
    float pw_s = validt ? lws[tc[p]] : 0.f;
    acc_num_s -= pw_s * lp;
    acc_den_s += pw_s;

    float e = earr[p];
    bool valida = validt && (e > 0.8f);
    float pw_a = valida ? lwa[tc[p]] : 0.f;
    acc_num_a -= pw_a * lp;
    acc_den_a += pw_a;

    int emv = emarr[p];
    float tf = (float)emv;
    float wb = (emv == 1) ? wpos : ((emv == 0) ? wneg : 0.f);
    float bce = fmaxf(e, 0.f) - e * tf + log1pf(__expf(-fabsf(e)));
    acc_bce += wb * bce;
  }

  #pragma unroll
  for (int off = 32; off > 0; off >>= 1) {
    acc_num_s += __shfl_down(acc_num_s, off);
    acc_den_s += __shfl_down(acc_den_s, off);
    acc_num_a += __shfl_down(acc_num_a, off);
    acc_den_a += __shfl_down(acc_den_a, off);
    acc_bce   += __shfl_down(acc_bce, off);
  }
  __shared__ float red[4][5];
  const int wave = tid >> 6;
  const int lane = tid & 63;
  if (lane == 0) {
    red[wave][0] = acc_num_s; red[wave][1] = acc_den_s;
    red[wave][2] = acc_num_a; red[wave][3] = acc_den_a;
    red[wave][4] = acc_bce;
  }
  __syncthreads();
  if (tid == 0) {
    float r0 = 0.f, r1 = 0.f, r2 = 0.f, r3 = 0.f, r4 = 0.f;
    #pragma unroll
    for (int wv = 0; wv < 4; ++wv) {
      r0 += red[wv][0]; r1 += red[wv][1]; r2 += red[wv][2];
      r3 += red[wv][3]; r4 += red[wv][4];
    }
    atomicAdd(&wsw->num_seg[n], (double)r0);
    atomicAdd(&wsw->den_seg[n], (double)r1);
    atomicAdd(&wsw->num_att[n], (double)r2);
    atomicAdd(&wsw->den_att[n], (double)r3);
    atomicAdd(&wsw->bce_sum,    (double)r4);
  }
}

// ---------------------------------------------------------------- finalize
__global__ void k_final(const Ws* __restrict__ ws, float* __restrict__ out) {
  if (threadIdx.x == 0 && blockIdx.x == 0) {
    double segl = 0.0, attl = 0.0;
    for (int i = 0; i < NB; ++i) {
      segl += ws->num_seg[i] / ws->den_seg[i];
      attl += ws->num_att[i] / ws->den_att[i];
    }
    double edgel = ws->bce_sum / (double)NPIX;
    out[0] = (float)(1.0 * segl + 0.3 * edgel + 0.1 * attl);
  }
}

// ---------------------------------------------------------------- launch
extern "C" void kernel_launch(void* const* d_in, const int* in_sizes, int n_in,
                              void* d_out, int out_size, void* d_ws, size_t ws_size,
                              hipStream_t stream) {
  const float* segin   = (const float*)d_in[0];
  const float* edgein  = (const float*)d_in[1];
  const int*   segmask = (const int*)d_in[2];
  const int*   edgemask= (const int*)d_in[3];
  Ws* ws = (Ws*)d_ws;
  float* out = (float*)d_out;

  hipLaunchKernelGGL(k_init,    dim3(1),              dim3(256), 0, stream, ws);
  hipLaunchKernelGGL(k_hist,    dim3(HW / 4096, NB),  dim3(256), 0, stream, segmask, edgein, edgemask, ws);
  hipLaunchKernelGGL(k_weights, dim3(1),              dim3(256), 0, stream, ws);
  hipLaunchKernelGGL(k_main,    dim3(HW / 1024, NB),  dim3(256), 0, stream, segin, edgein, segmask, edgemask, ws, ws);
  hipLaunchKernelGGL(k_final,   dim3(1),              dim3(1),   0, stream, ws, out);
}

// Round 3
// 345.759 us; speedup vs baseline: 1.0548x; 1.0291x over previous
//
#include <hip/hip_runtime.h>
#include <math.h>

#define CNUM 19
#define NB 4
#define HW 589824            // 768*768
#define NPIX 2359296         // NB*HW

// ---------------------------------------------------------------- workspace
struct Ws {
  unsigned int hist_seg[NB][CNUM];   // per-image class histogram of segmask
  unsigned int hist_att[NB][CNUM];   // per-image class histogram where edge>0.8
  unsigned int pos_num;              // edgemask == 1 count (global)
  unsigned int neg_num;              // edgemask == 0 count (global)
  double num_seg[NB];
  double den_seg[NB];
  double num_att[NB];
  double den_att[NB];
  double bce_sum;
};

// ---------------------------------------------------------------- init: zero ws
__global__ void k_init(Ws* ws) {
  unsigned int* p = (unsigned int*)ws;
  const int nwords = (int)(sizeof(Ws) / 4);
  for (int i = threadIdx.x; i < nwords; i += blockDim.x) p[i] = 0u;
}

// ---------------------------------------------------------------- histograms
// Ballot-based: no atomics in the hot loop. grid (HW/4096, NB) x 256.
// Per pixel: 1 ballot for att-mask, then 19 ballots for classes; att count
// comes from popc(class_mask & att_mask) — ~20 ballots/pixel instead of 40.
__global__ __launch_bounds__(256) void k_hist(const int* __restrict__ segmask,
                                              const float* __restrict__ edgein,
                                              const int* __restrict__ edgemask,
                                              Ws* __restrict__ ws) {
  const int n  = blockIdx.y;
  const int bx = blockIdx.x;
  const int tid = threadIdx.x;
  const int base = n * HW + bx * 4096 + tid * 4;

  unsigned int cs[CNUM], ca[CNUM];
  #pragma unroll
  for (int c = 0; c < CNUM; ++c) { cs[c] = 0u; ca[c] = 0u; }
  unsigned int cp = 0u, cn = 0u;

  #pragma unroll
  for (int it = 0; it < 4; ++it) {
    const int idx = base + it * 1024;
    int4   sv = *reinterpret_cast<const int4*>(segmask + idx);
    float4 e  = *reinterpret_cast<const float4*>(edgein + idx);
    int4   mv = *reinterpret_cast<const int4*>(edgemask + idx);
    int   sa[4] = {sv.x, sv.y, sv.z, sv.w};
    float ea[4] = {e.x, e.y, e.z, e.w};
    int   ma[4] = {mv.x, mv.y, mv.z, mv.w};
    #pragma unroll
    for (int p = 0; p < 4; ++p) {
      const int s = sa[p];
      const bool inb = ((unsigned)s) < (unsigned)CNUM;
      const unsigned long long attm = __ballot(ea[p] > 0.8f);
      #pragma unroll
      for (int c = 0; c < CNUM; ++c) {
        unsigned long long bm = __ballot(inb && (s == c));
        cs[c] += (unsigned)__popcll(bm);
        ca[c] += (unsigned)__popcll(bm & attm);
      }
      cp += (unsigned)__popcll(__ballot(ma[p] == 1));
      cn += (unsigned)__popcll(__ballot(ma[p] == 0));
    }
  }

  __shared__ unsigned int red[4][2 * CNUM + 2];
  const int wave = tid >> 6;
  const int lane = tid & 63;
  if (lane == 0) {
    #pragma unroll
    for (int c = 0; c < CNUM; ++c) { red[wave][c] = cs[c]; red[wave][CNUM + c] = ca[c]; }
    red[wave][2 * CNUM] = cp;
    red[wave][2 * CNUM + 1] = cn;
  }
  __syncthreads();
  if (tid < 2 * CNUM + 2) {
    unsigned int v = red[0][tid] + red[1][tid] + red[2][tid] + red[3][tid];
    if (tid < CNUM)               atomicAdd(&ws->hist_seg[n][tid], v);
    else if (tid < 2 * CNUM)      atomicAdd(&ws->hist_att[n][tid - CNUM], v);
    else if (tid == 2 * CNUM)     atomicAdd(&ws->pos_num, v);
    else                          atomicAdd(&ws->neg_num, v);
  }
}

// ---------------------------------------------------------------- main pass
// grid (HW/1024, NB) x 256; 4 pixels/thread. Stage all 19 channel float4
// loads before consuming (needs ~110 VGPRs -> launch_bounds(256,4) caps 128,
// 16 waves/CU). Weights computed per-block from the histograms (k_weights
// fused away).
__global__ __launch_bounds__(256, 4) void k_main(const float* __restrict__ segin,
                                                 const float* __restrict__ edgein,
                                                 const int* __restrict__ segmask,
                                                 const int* __restrict__ edgemask,
                                                 const Ws* __restrict__ ws,
                                                 Ws* __restrict__ wsw) {
  const int n = blockIdx.y;
  const int tid = threadIdx.x;
  const int hw4 = (blockIdx.x * 256 + tid) * 4;
  const int idx4 = n * HW + hw4;
  const float* base = segin + (size_t)n * CNUM * HW + hw4;

  // compute per-image class weights from histograms into LDS
  __shared__ float lws[CNUM], lwa[CNUM];
  if (tid < CNUM) {
    float total = 0.f;
    #pragma unroll
    for (int i = 0; i < CNUM; ++i) total += (float)ws->hist_seg[n][i];
    float bins = (float)ws->hist_seg[n][tid];
    lws[tid] = (bins != 0.f ? (1.0f - bins / total) : 0.f) + 1.0f;
  } else if (tid >= 64 && tid < 64 + CNUM) {
    int c = tid - 64;
    float total = 0.f;
    #pragma unroll
    for (int i = 0; i < CNUM; ++i) total += (float)ws->hist_att[n][i];
    float bins = (float)ws->hist_att[n][c];
    lwa[c] = (bins != 0.f ? (1.0f - bins / total) : 0.f) + 1.0f;
  }

  // stage ALL loads first: 19 channel float4 + masks/edge
  float4 xv[CNUM];
  #pragma unroll
  for (int c = 0; c < CNUM; ++c)
    xv[c] = *reinterpret_cast<const float4*>(base + (size_t)c * HW);
  int4   tm = *reinterpret_cast<const int4*>(segmask + idx4);
  float4 ev = *reinterpret_cast<const float4*>(edgein + idx4);
  int4   em = *reinterpret_cast<const int4*>(edgemask + idx4);

  const unsigned int pn = ws->pos_num, nn = ws->neg_num;
  const float inv_sum = 1.0f / (float)(pn + nn);
  const float wpos = (float)nn * inv_sum;
  const float wneg = (float)pn * inv_sum;

  __syncthreads();

  int   tarr[4]  = {tm.x, tm.y, tm.z, tm.w};
  float earr[4]  = {ev.x, ev.y, ev.z, ev.w};
  int   emarr[4] = {em.x, em.y, em.z, em.w};

  float acc_num_s = 0.f, acc_den_s = 0.f, acc_num_a = 0.f, acc_den_a = 0.f, acc_bce = 0.f;
  #pragma unroll
  for (int p = 0; p < 4; ++p) {
    const int t = tarr[p];
    const int tc = min(max(t, 0), CNUM - 1);
    const float* xp = (const float*)&xv[0] + p;   // stride 4 floats per channel
    float s = 0.f, xt = 0.f;
    #pragma unroll
    for (int c = 0; c < CNUM; ++c) {
      float v = xp[4 * c];
      s += __expf(v);
      xt = (tc == c) ? v : xt;
    }
    float lp = xt - __logf(s);

    bool validt = (t != 255);
    float pw_s = validt ? lws[tc] : 0.f;
    acc_num_s -= pw_s * lp;
    acc_den_s += pw_s;

    float e = earr[p];
    bool valida = validt && (e > 0.8f);
    float pw_a = valida ? lwa[tc] : 0.f;
    acc_num_a -= pw_a * lp;
    acc_den_a += pw_a;

    int emv = emarr[p];
    float tf = (float)emv;
    float wb = (emv == 1) ? wpos : ((emv == 0) ? wneg : 0.f);
    float bce = fmaxf(e, 0.f) - e * tf + log1pf(__expf(-fabsf(e)));
    acc_bce += wb * bce;
  }

  #pragma unroll
  for (int off = 32; off > 0; off >>= 1) {
    acc_num_s += __shfl_down(acc_num_s, off);
    acc_den_s += __shfl_down(acc_den_s, off);
    acc_num_a += __shfl_down(acc_num_a, off);
    acc_den_a += __shfl_down(acc_den_a, off);
    acc_bce   += __shfl_down(acc_bce, off);
  }
  __shared__ float red[4][5];
  const int wave = tid >> 6;
  const int lane = tid & 63;
  if (lane == 0) {
    red[wave][0] = acc_num_s; red[wave][1] = acc_den_s;
    red[wave][2] = acc_num_a; red[wave][3] = acc_den_a;
    red[wave][4] = acc_bce;
  }
  __syncthreads();
  if (tid == 0) {
    float r0 = 0.f, r1 = 0.f, r2 = 0.f, r3 = 0.f, r4 = 0.f;
    #pragma unroll
    for (int wv = 0; wv < 4; ++wv) {
      r0 += red[wv][0]; r1 += red[wv][1]; r2 += red[wv][2];
      r3 += red[wv][3]; r4 += red[wv][4];
    }
    atomicAdd(&wsw->num_seg[n], (double)r0);
    atomicAdd(&wsw->den_seg[n], (double)r1);
    atomicAdd(&wsw->num_att[n], (double)r2);
    atomicAdd(&wsw->den_att[n], (double)r3);
    atomicAdd(&wsw->bce_sum,    (double)r4);
  }
}

// ---------------------------------------------------------------- finalize
__global__ void k_final(const Ws* __restrict__ ws, float* __restrict__ out) {
  if (threadIdx.x == 0 && blockIdx.x == 0) {
    double segl = 0.0, attl = 0.0;
    for (int i = 0; i < NB; ++i) {
      segl += ws->num_seg[i] / ws->den_seg[i];
      attl += ws->num_att[i] / ws->den_att[i];
    }
    double edgel = ws->bce_sum / (double)NPIX;
    out[0] = (float)(1.0 * segl + 0.3 * edgel + 0.1 * attl);
  }
}

// ---------------------------------------------------------------- launch
extern "C" void kernel_launch(void* const* d_in, const int* in_sizes, int n_in,
                              void* d_out, int out_size, void* d_ws, size_t ws_size,
                              hipStream_t stream) {
  const float* segin   = (const float*)d_in[0];
  const float* edgein  = (const float*)d_in[1];
  const int*   segmask = (const int*)d_in[2];
  const int*   edgemask= (const int*)d_in[3];
  Ws* ws = (Ws*)d_ws;
  float* out = (float*)d_out;

  hipLaunchKernelGGL(k_init,  dim3(1),             dim3(256), 0, stream, ws);
  hipLaunchKernelGGL(k_hist,  dim3(HW / 4096, NB), dim3(256), 0, stream, segmask, edgein, edgemask, ws);
  hipLaunchKernelGGL(k_main,  dim3(HW / 1024, NB), dim3(256), 0, stream, segin, edgein, segmask, edgemask, ws, ws);
  hipLaunchKernelGGL(k_final, dim3(1),             dim3(1),   0, stream, ws, out);
}